// Round 15
// baseline (505.271 us; speedup 1.0000x reference)
//
#include <hip/hip_runtime.h>
#include <hip/hip_bf16.h>

typedef __attribute__((ext_vector_type(8))) short bfrag8;
typedef __attribute__((ext_vector_type(4))) float f32x4;
typedef __attribute__((ext_vector_type(4))) unsigned int u32x4;

#define IS2_SCALE 0.84932180028801907f   /* sqrt(0.5*log2(e)): exp2(-(u)^2)=exp(-t^2/2) */
#define W1_SCALE  0.46971724f            /* is2*W1_SCALE = 1/(sqrt(2*3.14159)*std) fold */

#if __has_builtin(__builtin_amdgcn_exp2f)
#define GEXP(x) __builtin_amdgcn_exp2f(x)
#else
__device__ __forceinline__ float gexp_asm(float x) {
  float r; asm("v_exp_f32 %0, %1" : "=v"(r) : "v"(x)); return r;
}
#define GEXP(x) gexp_asm(x)
#endif

__device__ __forceinline__ unsigned short f2bf(float x) {
  union { float f; unsigned u; } v; v.f = x;
  unsigned r = v.u + 0x7fffu + ((v.u >> 16) & 1u);
  return (unsigned short)(r >> 16);
}
__device__ __forceinline__ unsigned cvtpk(float lo, float hi) {
  unsigned r;
  asm("v_cvt_pk_bf16_f32 %0, %1, %2" : "=v"(r) : "v"(lo), "v"(hi));
  return r;
}
__device__ __forceinline__ float rcpa(float x) {
  float r; asm("v_rcp_f32 %0, %1" : "=v"(r) : "v"(x)); return r;
}
// tanh-form GELU: x/(1+exp2(x*(C0+C1*x^2)))
__device__ __forceinline__ float gelu_fast(float x) {
  float x2 = x * x;
  float w = __builtin_fmaf(x2, -0.1029488f, -2.3022078f);
  float e = GEXP(x * w);
  return x * rcpa(e + 1.0f);
}

// A-fragment pair (rows lr, lr+16 of the wave tile) for k-block kb
__device__ __forceinline__ void gauss_frags(const f32x4* prm4, const f32x4 xa, const f32x4 xb,
                                            int kb, int lg, bfrag8* A0, bfrag8* A1) {
  const int k0 = kb * 32 + lg * 8;
  const float x0 = xa[kb >> 2], x1 = xb[kb >> 2];
  unsigned pk0[4], pk1[4];
#pragma unroll
  for (int q = 0; q < 4; ++q) {
    f32x4 P = prm4[(k0 >> 1) + q];     // {mis2_e, is2_e, mis2_o, is2_o}
    float u00 = __builtin_fmaf(x0, P[1], P[0]);
    float u01 = __builtin_fmaf(x0, P[3], P[2]);
    float u10 = __builtin_fmaf(x1, P[1], P[0]);
    float u11 = __builtin_fmaf(x1, P[3], P[2]);
    pk0[q] = cvtpk(P[1] * GEXP(-(u00 * u00)), P[3] * GEXP(-(u01 * u01)));
    pk1[q] = cvtpk(P[1] * GEXP(-(u10 * u10)), P[3] * GEXP(-(u11 * u11)));
  }
  u32x4 av0 = {pk0[0], pk0[1], pk0[2], pk0[3]};
  u32x4 av1 = {pk1[0], pk1[1], pk1[2], pk1[3]};
  *A0 = __builtin_bit_cast(bfrag8, av0);
  *A1 = __builtin_bit_cast(bfrag8, av1);
}

// ---------------- prep: weights->bf16 (W1 pre-scaled), packed gaussian params -
__global__ void prep_kernel(const float* __restrict__ means, const float* __restrict__ stds,
                            const float* __restrict__ W1, const float* __restrict__ W2,
                            unsigned short* __restrict__ W1bf, unsigned short* __restrict__ W2bf,
                            float* __restrict__ prm /* [512][2]: mis2, is2 */) {
  int t = blockIdx.x * blockDim.x + threadIdx.x;
  int stride = gridDim.x * blockDim.x;
  for (int i = t; i < 512 * 512; i += stride) W1bf[i] = f2bf(W1[i] * W1_SCALE);
  for (int i = t; i < 32 * 512; i += stride) W2bf[i] = f2bf(W2[i]);
  for (int i = t; i < 512; i += stride) {
    float s = fabsf(stds[i]) + 0.01f;
    float is2 = (1.0f / s) * IS2_SCALE;
    prm[2 * i] = -means[i] * is2;        // mis2
    prm[2 * i + 1] = is2;                // is2  (coef folded into W1)
  }
}

// ---------------- init: out = b2 broadcast (atomic partials add onto this) ----
__global__ void init_out(const float* __restrict__ b2, float* __restrict__ out) {
  int i = blockIdx.x * blockDim.x + threadIdx.x;    // f32x4 index, 2097152 total
  float v = b2[(i >> 14) & 31];                     // o = (i*4 >> 16) & 31
  f32x4 vv = {v, v, v, v};
  *reinterpret_cast<f32x4*>(out + (size_t)i * 4) = vv;
}

// ---------------- fused main kernel (barrier-free K-loop) ---------------------
// Grid 2048 = 4 h-chunks x 512 row-groups. Block: 1024 thr = 16 waves, 512 rows,
// one 128-col W1 chunk staged ONCE in LDS (128KB). Wave = 32 rows x 128 chunk
// cols; K-loop (16 steps) has NO barriers: A (gaussian) in regs, B static LDS.
// Epilogue: gelu -> per-wave swizzled scratch (reusing dead W1c) -> GEMM2 with
// W2 chunk from L1 -> atomicAdd partial out.
__global__ __launch_bounds__(1024, 4) void fused_kernel(
    const float* __restrict__ rpe, const unsigned short* __restrict__ W1bf,
    const unsigned short* __restrict__ W2bf, const float* __restrict__ prm,
    const float* __restrict__ b1, float* __restrict__ out) {
  __shared__ __attribute__((aligned(16))) char lds[131072 + 4096];
  float* prm_s = (float*)(lds + 131072);

  const int tid = threadIdx.x;
  const int bid = blockIdx.x;
  const int c = bid & 3;                 // h-chunk
  const int rb = (bid >> 2) * 512;       // flat row base

  prm_s[tid] = prm[tid];

  // ---- stage W1 chunk: LDS frag layout addr = ks*8192 + J*1024 + lg*256 + jr*16
  const char* Wc = (const char*)W1bf;
#pragma unroll
  for (int i = 0; i < 8; ++i) {
    int c16 = i * 1024 + tid;            // 16B-chunk index 0..8191
    int ks = c16 >> 9;
    int J  = (c16 >> 6) & 7;
    int lgs = (c16 >> 4) & 3;
    int jr = c16 & 15;
    const void* gp = Wc + ((size_t)(c * 128 + J * 16 + jr) * 512 + ks * 32 + lgs * 8) * 2;
    void* lp = lds + c16 * 16;
    __builtin_amdgcn_global_load_lds(
        (const __attribute__((address_space(1))) void*)gp,
        (__attribute__((address_space(3))) void*)lp, 16, 0, 0);
  }
  __syncthreads();                       // W1c + prm ready (drains vmcnt)

  const int w = tid >> 6, l = tid & 63;
  const int lr = l & 15, lg = l >> 4;
  const int r0w = rb + w * 32;           // this wave's 32 rows

  const f32x4 xa = *(const f32x4*)(rpe + (size_t)(r0w + lr) * 4);
  const f32x4 xb = *(const f32x4*)(rpe + (size_t)(r0w + 16 + lr) * 4);
  const f32x4* prm4 = (const f32x4*)prm_s;

  f32x4 zv = {0.f, 0.f, 0.f, 0.f};
  f32x4 acc[2][8];
#pragma unroll
  for (int mf = 0; mf < 2; ++mf)
#pragma unroll
    for (int J = 0; J < 8; ++J) acc[mf][J] = zv;

  // ---- barrier-free K-loop: 16 steps x (16 gauss + 8 ds_read + 16 MFMA)
#pragma unroll
  for (int ks = 0; ks < 16; ++ks) {
    bfrag8 a0, a1;
    gauss_frags(prm4, xa, xb, ks, lg, &a0, &a1);
    const char* Bb = lds + ks * 8192 + lg * 256 + lr * 16;
#pragma unroll
    for (int J = 0; J < 8; ++J) {
      bfrag8 b = *(const bfrag8*)(Bb + J * 1024);
      acc[0][J] = __builtin_amdgcn_mfma_f32_16x16x32_bf16(a0, b, acc[0][J], 0, 0, 0);
      acc[1][J] = __builtin_amdgcn_mfma_f32_16x16x32_bf16(a1, b, acc[1][J], 0, 0, 0);
    }
  }
  __syncthreads();                       // all waves done with W1c -> scratch reuse

  // ---- epilogue: bias + gelu -> per-wave swizzled scratch [32r][128h] bf16
  char* scr = lds + w * 8192;
#pragma unroll
  for (int mf = 0; mf < 2; ++mf) {
#pragma unroll
    for (int J = 0; J < 8; ++J) {
      float bb = b1[c * 128 + J * 16 + lr];
#pragma unroll
      for (int q = 0; q < 4; ++q) {
        float g = gelu_fast(acc[mf][J][q] + bb);
        int r = mf * 16 + lg * 4 + q;
        int byte = (r * 256 + (J * 16 + lr) * 2) ^ ((r & 7) << 4);
        *(unsigned short*)(scr + byte) = f2bf(g);
      }
    }
  }

  // ---- GEMM2 partial: out[32r][32o] over this chunk's 128 h
  bfrag8 w2f[2][4];
#pragma unroll
  for (int og = 0; og < 2; ++og)
#pragma unroll
    for (int kk = 0; kk < 4; ++kk)
      w2f[og][kk] = *(const bfrag8*)(W2bf + (size_t)(og * 16 + lr) * 512 + c * 128 + kk * 32 + lg * 8);

  asm volatile("s_waitcnt lgkmcnt(0)" ::: "memory");   // scratch writes visible
  f32x4 acc2[2][2];
  acc2[0][0] = zv; acc2[0][1] = zv; acc2[1][0] = zv; acc2[1][1] = zv;
#pragma unroll
  for (int rf = 0; rf < 2; ++rf) {
#pragma unroll
    for (int kk = 0; kk < 4; ++kk) {
      int r = rf * 16 + lr;
      int byte = (r * 256 + kk * 64 + lg * 16) ^ ((r & 7) << 4);
      bfrag8 a = *(const bfrag8*)(scr + byte);
      acc2[rf][0] = __builtin_amdgcn_mfma_f32_16x16x32_bf16(a, w2f[0][kk], acc2[rf][0], 0, 0, 0);
      acc2[rf][1] = __builtin_amdgcn_mfma_f32_16x16x32_bf16(a, w2f[1][kk], acc2[rf][1], 0, 0, 0);
    }
  }

  // ---- atomic accumulate: out[b][o][m][n], flat = bI*2097152 + o*65536 + low16
  const int bI = rb >> 16;
  float* ob = out + (size_t)bI * 2097152 + (rb & 65535) + w * 32;
#pragma unroll
  for (int rf = 0; rf < 2; ++rf)
#pragma unroll
    for (int og = 0; og < 2; ++og)
#pragma unroll
      for (int q = 0; q < 4; ++q) {
        int o = og * 16 + lr;
        int r = rf * 16 + lg * 4 + q;
        atomicAdd(ob + (size_t)o * 65536 + r, acc2[rf][og][q]);
      }
}

// ---------------- launch ------------------------------------------------------
extern "C" void kernel_launch(void* const* d_in, const int* in_sizes, int n_in,
                              void* d_out, int out_size, void* d_ws, size_t ws_size,
                              hipStream_t stream) {
  const float* rpe   = (const float*)d_in[0];
  const float* means = (const float*)d_in[1];
  const float* stds  = (const float*)d_in[2];
  const float* W1    = (const float*)d_in[3];
  const float* b1    = (const float*)d_in[4];
  const float* W2    = (const float*)d_in[5];
  const float* b2    = (const float*)d_in[6];
  float* out = (float*)d_out;

  char* ws = (char*)d_ws;
  unsigned short* W1bf = (unsigned short*)ws;             // 512*512*2 = 524288 B
  unsigned short* W2bf = (unsigned short*)(ws + 524288);  // 32*512*2  =  32768 B
  float* prm = (float*)(ws + 557056);                     // 512*2*4   =   4096 B

  prep_kernel<<<256, 256, 0, stream>>>(means, stds, W1, W2, W1bf, W2bf, prm);
  init_out<<<8192, 256, 0, stream>>>(b2, out);            // out = b2 broadcast
  fused_kernel<<<2048, 1024, 0, stream>>>(rpe, W1bf, W2bf, prm, b1, out);
}

// Round 16
// 285.338 us; speedup vs baseline: 1.7708x; 1.7708x over previous
//
#include <hip/hip_runtime.h>
#include <hip/hip_bf16.h>

typedef __attribute__((ext_vector_type(8))) short bfrag8;
typedef __attribute__((ext_vector_type(4))) float f32x4;
typedef __attribute__((ext_vector_type(4))) unsigned int u32x4;

#define IS2_SCALE 0.84932180028801907f   /* sqrt(0.5*log2(e)): exp2(-(u)^2)=exp(-t^2/2) */
#define W1_SCALE  0.46971724f            /* folds 1/(sqrt(2pi)*std) into W1 via is2 */

#if __has_builtin(__builtin_amdgcn_exp2f)
#define GEXP(x) __builtin_amdgcn_exp2f(x)
#else
__device__ __forceinline__ float gexp_asm(float x) {
  float r; asm("v_exp_f32 %0, %1" : "=v"(r) : "v"(x)); return r;
}
#define GEXP(x) gexp_asm(x)
#endif

__device__ __forceinline__ unsigned short f2bf(float x) {
  union { float f; unsigned u; } v; v.f = x;
  unsigned r = v.u + 0x7fffu + ((v.u >> 16) & 1u);
  return (unsigned short)(r >> 16);
}
__device__ __forceinline__ unsigned cvtpk(float lo, float hi) {
  unsigned r;
  asm("v_cvt_pk_bf16_f32 %0, %1, %2" : "=v"(r) : "v"(lo), "v"(hi));
  return r;
}
__device__ __forceinline__ float rcpa(float x) {
  float r; asm("v_rcp_f32 %0, %1" : "=v"(r) : "v"(x)); return r;
}
// tanh-form GELU: x/(1+exp2(x*(C0+C1*x^2)))
__device__ __forceinline__ float gelu_fast(float x) {
  float x2 = x * x;
  float w = __builtin_fmaf(x2, -0.1029488f, -2.3022078f);
  float e = GEXP(x * w);
  return x * rcpa(e + 1.0f);
}

// A-fragment pair (rows r0, r0+16) for K-block kb: 16 gaussians
__device__ __forceinline__ void gauss_frags(const f32x4* prm4, const f32x4 xa, const f32x4 xb,
                                            int kb, int lg, bfrag8* A0, bfrag8* A1) {
  const int k0 = kb * 32 + lg * 8;
  const float x0 = xa[kb >> 2], x1 = xb[kb >> 2];
  unsigned pk0[4], pk1[4];
#pragma unroll
  for (int q = 0; q < 4; ++q) {
    f32x4 P = prm4[(k0 >> 1) + q];     // {mis2_e, is2_e, mis2_o, is2_o}
    float u00 = __builtin_fmaf(x0, P[1], P[0]);
    float u01 = __builtin_fmaf(x0, P[3], P[2]);
    float u10 = __builtin_fmaf(x1, P[1], P[0]);
    float u11 = __builtin_fmaf(x1, P[3], P[2]);
    pk0[q] = cvtpk(P[1] * GEXP(-(u00 * u00)), P[3] * GEXP(-(u01 * u01)));
    pk1[q] = cvtpk(P[1] * GEXP(-(u10 * u10)), P[3] * GEXP(-(u11 * u11)));
  }
  u32x4 av0 = {pk0[0], pk0[1], pk0[2], pk0[3]};
  u32x4 av1 = {pk1[0], pk1[1], pk1[2], pk1[3]};
  *A0 = __builtin_bit_cast(bfrag8, av0);
  *A1 = __builtin_bit_cast(bfrag8, av1);
}

// ---------------- prep: weights->bf16 (W1 pre-scaled), packed gaussian params -
__global__ void prep_kernel(const float* __restrict__ means, const float* __restrict__ stds,
                            const float* __restrict__ W1, const float* __restrict__ W2,
                            unsigned short* __restrict__ W1bf, unsigned short* __restrict__ W2bf,
                            float* __restrict__ prm /* [512][2]: mis2, is2 */) {
  int t = blockIdx.x * blockDim.x + threadIdx.x;
  int stride = gridDim.x * blockDim.x;
  for (int i = t; i < 512 * 512; i += stride) W1bf[i] = f2bf(W1[i] * W1_SCALE);
  for (int i = t; i < 32 * 512; i += stride) W2bf[i] = f2bf(W2[i]);
  for (int i = t; i < 512; i += stride) {
    float s = fabsf(stds[i]) + 0.01f;
    float is2 = (1.0f / s) * IS2_SCALE;
    prm[2 * i] = -means[i] * is2;        // mis2
    prm[2 * i + 1] = is2;                // is2  (coef folded into W1)
  }
}

// ---------------- fused main kernel ------------------------------------------
// 1024 threads = 16 waves (4M x 4N), 128 rows/block, BK=32. TRIPLE-buffered B
// staging with a SINGLE barrier per K-step (16 rendezvous vs 32): the stage at
// iter kb targets buf (kb+2)%3, last read at iter kb-1, and barrier(kb)
// separates those. Prefetch depth 2 => vmcnt(2) is pre-satisfied. gsl A-frag
// broadcast (dup 1) as in R14.
__global__ __launch_bounds__(1024, 4) void fused_kernel(
    const float* __restrict__ rpe, const unsigned short* __restrict__ W1bf,
    const unsigned short* __restrict__ W2bf, const float* __restrict__ prm,
    const float* __restrict__ b1, const float* __restrict__ b2,
    float* __restrict__ out) {
  __shared__ __attribute__((aligned(16))) char lds[131072 + 4096 + 2048 + 2048 + 16384];
  // [0,128K): 3x32KB B buffers -> h[128][512] bf16 -> out[128][33] f32
  float* prm_s = (float*)(lds + 131072);                  // [512][2] = 4KB
  float* rpe_s = (float*)(lds + 131072 + 4096);           // [128][4] = 2KB
  float* b1_s  = (float*)(lds + 131072 + 4096 + 2048);    // [512]    = 2KB
  char*  gsl   = lds + 131072 + 4096 + 2048 + 2048;       // [2][4][128]x16B = 16KB

  const int tid = threadIdx.x;
  const int rb = blockIdx.x * 128;

  if (tid < 512) rpe_s[tid] = rpe[rb * 4 + tid];
  prm_s[tid] = prm[tid];                 // 1024 floats
  if (tid < 512) b1_s[tid] = b1[tid];

  int goff[2];
#pragma unroll
  for (int i = 0; i < 2; ++i) {
    int c = i * 1024 + tid;
    int j = ((c >> 6) << 4) + (c & 15);
    goff[i] = j * 512 + ((c >> 4) & 3) * 8;
  }
  const char* Wc = (const char*)W1bf;

#define STAGE(buf, kb)                                                          \
  {                                                                             \
    _Pragma("unroll") for (int i_ = 0; i_ < 2; ++i_) {                          \
      const void* gp = (const void*)(Wc + (size_t)goff[i_] * 2 + (kb) * 64);    \
      void* lp = (void*)(lds + (buf) * 32768 + i_ * 16384 + tid * 16);          \
      __builtin_amdgcn_global_load_lds(                                         \
          (const __attribute__((address_space(1))) void*)gp,                    \
          (__attribute__((address_space(3))) void*)lp, 16, 0, 0);               \
    }                                                                           \
  }

  STAGE(0, 0);
  STAGE(1, 1);
  __syncthreads();   // full drain: rpe/prm/b1 + B slices 0,1 collectively ready

  const int w = tid >> 6, l = tid & 63;
  const int lr = l & 15, lg = l >> 4;
  const int mw = w >> 2, nw = w & 3;     // 4 M-waves x 4 N-waves
  const int r0 = mw * 32 + lr;           // A rows r0 and r0+16

  const f32x4 xa = *(const f32x4*)&rpe_s[r0 * 4];
  const f32x4 xb = *(const f32x4*)&rpe_s[(r0 + 16) * 4];
  const f32x4* prm4 = (const f32x4*)prm_s;

  char* gw = gsl + lg * 2048 + r0 * 16;          // writer base (slot 0)
  const char* gr = gsl + lg * 2048 + r0 * 16;    // reader base (slot 0)

  // ---- prologue: nw0 waves compute + write gsl slice 0
  bfrag8 acur0, acur1;
  if (nw == 0) {
    gauss_frags(prm4, xa, xb, 0, lg, &acur0, &acur1);
    *(bfrag8*)(gw) = acur0;
    *(bfrag8*)(gw + 256) = acur1;
  }
  __syncthreads();   // slice 0 visible to all

  f32x4 zv = {0.f, 0.f, 0.f, 0.f};
  f32x4 acc[2][8];
#pragma unroll
  for (int mf = 0; mf < 2; ++mf)
#pragma unroll
    for (int nf = 0; nf < 8; ++nf) acc[mf][nf] = zv;

#pragma unroll
  for (int kb = 0; kb < 16; ++kb) {
    // ---- wait for OWN 2 loads of buf kb%3 (issued 2 iters ago: pre-satisfied)
    if (kb < 15) {
      asm volatile("s_waitcnt vmcnt(2)" ::: "memory");
    } else {
      asm volatile("s_waitcnt vmcnt(0)" ::: "memory");
    }
    __builtin_amdgcn_s_barrier();            // single rendezvous per K-step
    __builtin_amdgcn_sched_barrier(0);

    if (kb < 14) STAGE((kb + 2) % 3, kb + 2);

    const int slot = (kb & 1) * 8192;
    bfrag8 a0, a1, an0, an1;
    if (nw == 0) {
      a0 = acur0; a1 = acur1;
      if (kb < 15) {
        gauss_frags(prm4, xa, xb, kb + 1, lg, &an0, &an1);
        char* gwn = gw + (((kb + 1) & 1) * 8192);
        *(bfrag8*)(gwn) = an0;
        *(bfrag8*)(gwn + 256) = an1;
        asm volatile("s_waitcnt lgkmcnt(0)" ::: "memory");  // write retired pre-next-barrier
      }
    } else {
      a0 = *(const bfrag8*)(gr + slot);          // slice kb (written last iter)
      a1 = *(const bfrag8*)(gr + slot + 256);
    }

    // ---- B fragments from buf kb%3 (8 reads, reused by both row-frags)
    const char* Bbase = lds + (kb % 3) * 32768 + nw * 8192 + lg * 256 + lr * 16;
    __builtin_amdgcn_s_setprio(1);
#pragma unroll
    for (int nf = 0; nf < 8; ++nf) {
      bfrag8 b = *(const bfrag8*)(Bbase + nf * 1024);
      acc[0][nf] = __builtin_amdgcn_mfma_f32_16x16x32_bf16(a0, b, acc[0][nf], 0, 0, 0);
      acc[1][nf] = __builtin_amdgcn_mfma_f32_16x16x32_bf16(a1, b, acc[1][nf], 0, 0, 0);
    }
    __builtin_amdgcn_s_setprio(0);

    if (nw == 0 && kb < 15) { acur0 = an0; acur1 = an1; }
    // no second barrier: triple buffering makes the stage target safe
  }
  __syncthreads();   // all B reads done -> safe to overlay h on buffer region

  // ---- bias + fast GELU -> h in LDS [128][512] bf16, XOR-swizzled rows
  unsigned short* hbuf = (unsigned short*)lds;
#pragma unroll
  for (int mf = 0; mf < 2; ++mf) {
#pragma unroll
    for (int nf = 0; nf < 8; nf += 2) {
      int col0 = nw * 128 + nf * 16 + lr;
      int col1 = col0 + 16;
      float bb0 = b1_s[col0], bb1 = b1_s[col1];
#pragma unroll
      for (int bi = 0; bi < 4; ++bi) {
        float g0 = gelu_fast(acc[mf][nf][bi] + bb0);
        float g1 = gelu_fast(acc[mf][nf + 1][bi] + bb1);
        unsigned pr = cvtpk(g0, g1);
        int hrow = mw * 32 + mf * 16 + lg * 4 + bi;
        int base = hrow * 1024, sw = (hrow & 7) << 4;
        *(unsigned short*)((char*)hbuf + base + ((col0 * 2) ^ sw)) = (unsigned short)pr;
        *(unsigned short*)((char*)hbuf + base + ((col1 * 2) ^ sw)) = (unsigned short)(pr >> 16);
      }
    }
  }
  __syncthreads();

  // ---- GEMM2: out[128][32] = h @ W2^T. 16 waves: 8(row-tiles) x 2(col-tiles).
  const int rt = w >> 1, ct = w & 1;
  f32x4 acc2 = zv;
  const int row2 = rt * 16 + lr;
  for (int kb = 0; kb < 16; ++kb) {
    int cb = (kb * 64 + lg * 16) ^ ((row2 & 7) << 4);
    bfrag8 a = *(const bfrag8*)((char*)hbuf + row2 * 1024 + cb);
    bfrag8 b = *(const bfrag8*)(W2bf + (size_t)(ct * 16 + lr) * 512 + kb * 32 + lg * 8);
    acc2 = __builtin_amdgcn_mfma_f32_16x16x32_bf16(a, b, acc2, 0, 0, 0);
  }
  float b2v = b2[ct * 16 + lr];
  __syncthreads();                     // all h reads done -> safe to overlay

  float* ob = (float*)lds;             // [128][33] padded f32
#pragma unroll
  for (int bi = 0; bi < 4; ++bi)
    ob[(rt * 16 + lg * 4 + bi) * 33 + (ct * 16 + lr)] = acc2[bi] + b2v;
  __syncthreads();

  // ---- store transposed: out[b][o][m][n], 128 contiguous n per head
  const int bI = rb >> 16, mI = (rb >> 8) & 255, n0 = rb & 255;
  float* obase = out + ((size_t)(bI * 32) * 256 + mI) * 256 + n0;
#pragma unroll
  for (int p = 0; p < 4; ++p) {
    int e = tid + p * 1024;            // 0..4095
    int o = e >> 7, i = e & 127;
    obase[(size_t)o * 65536 + i] = ob[i * 33 + o];
  }
#undef STAGE
}

// ---------------- launch ------------------------------------------------------
extern "C" void kernel_launch(void* const* d_in, const int* in_sizes, int n_in,
                              void* d_out, int out_size, void* d_ws, size_t ws_size,
                              hipStream_t stream) {
  const float* rpe   = (const float*)d_in[0];
  const float* means = (const float*)d_in[1];
  const float* stds  = (const float*)d_in[2];
  const float* W1    = (const float*)d_in[3];
  const float* b1    = (const float*)d_in[4];
  const float* W2    = (const float*)d_in[5];
  const float* b2    = (const float*)d_in[6];
  float* out = (float*)d_out;

  char* ws = (char*)d_ws;
  unsigned short* W1bf = (unsigned short*)ws;             // 512*512*2 = 524288 B
  unsigned short* W2bf = (unsigned short*)(ws + 524288);  // 32*512*2  =  32768 B
  float* prm = (float*)(ws + 557056);                     // 512*2*4   =   4096 B

  prep_kernel<<<256, 256, 0, stream>>>(means, stds, W1, W2, W1bf, W2bf, prm);
  fused_kernel<<<2048, 1024, 0, stream>>>(rpe, W1bf, W2bf, prm, b1, b2, out);
}

// Round 17
// 271.794 us; speedup vs baseline: 1.8590x; 1.0498x over previous
//
#include <hip/hip_runtime.h>
#include <hip/hip_bf16.h>

typedef __attribute__((ext_vector_type(8))) short bfrag8;
typedef __attribute__((ext_vector_type(4))) float f32x4;
typedef __attribute__((ext_vector_type(4))) unsigned int u32x4;

#define IS2_SCALE 0.84932180028801907f   /* sqrt(0.5*log2(e)): exp2(-(u)^2)=exp(-t^2/2) */
#define W1_SCALE  0.46971724f            /* folds 1/(sqrt(2pi)*std) into W1 via is2 */

#if __has_builtin(__builtin_amdgcn_exp2f)
#define GEXP(x) __builtin_amdgcn_exp2f(x)
#else
__device__ __forceinline__ float gexp_asm(float x) {
  float r; asm("v_exp_f32 %0, %1" : "=v"(r) : "v"(x)); return r;
}
#define GEXP(x) gexp_asm(x)
#endif

__device__ __forceinline__ unsigned short f2bf(float x) {
  union { float f; unsigned u; } v; v.f = x;
  unsigned r = v.u + 0x7fffu + ((v.u >> 16) & 1u);
  return (unsigned short)(r >> 16);
}
__device__ __forceinline__ unsigned cvtpk(float lo, float hi) {
  unsigned r;
  asm("v_cvt_pk_bf16_f32 %0, %1, %2" : "=v"(r) : "v"(lo), "v"(hi));
  return r;
}
__device__ __forceinline__ float rcpa(float x) {
  float r; asm("v_rcp_f32 %0, %1" : "=v"(r) : "v"(x)); return r;
}
// tanh-form GELU: x/(1+exp2(x*(C0+C1*x^2)))
__device__ __forceinline__ float gelu_fast(float x) {
  float x2 = x * x;
  float w = __builtin_fmaf(x2, -0.1029488f, -2.3022078f);
  float e = GEXP(x * w);
  return x * rcpa(e + 1.0f);
}

// A-fragment pair (rows r0, r0+16) for K-block kb: 16 gaussians
__device__ __forceinline__ void gauss_frags(const f32x4* prm4, const f32x4 xa, const f32x4 xb,
                                            int kb, int lg, bfrag8* A0, bfrag8* A1) {
  const int k0 = kb * 32 + lg * 8;
  const float x0 = xa[kb >> 2], x1 = xb[kb >> 2];
  unsigned pk0[4], pk1[4];
#pragma unroll
  for (int q = 0; q < 4; ++q) {
    f32x4 P = prm4[(k0 >> 1) + q];     // {mis2_e, is2_e, mis2_o, is2_o}
    float u00 = __builtin_fmaf(x0, P[1], P[0]);
    float u01 = __builtin_fmaf(x0, P[3], P[2]);
    float u10 = __builtin_fmaf(x1, P[1], P[0]);
    float u11 = __builtin_fmaf(x1, P[3], P[2]);
    pk0[q] = cvtpk(P[1] * GEXP(-(u00 * u00)), P[3] * GEXP(-(u01 * u01)));
    pk1[q] = cvtpk(P[1] * GEXP(-(u10 * u10)), P[3] * GEXP(-(u11 * u11)));
  }
  u32x4 av0 = {pk0[0], pk0[1], pk0[2], pk0[3]};
  u32x4 av1 = {pk1[0], pk1[1], pk1[2], pk1[3]};
  *A0 = __builtin_bit_cast(bfrag8, av0);
  *A1 = __builtin_bit_cast(bfrag8, av1);
}

// ---------------- prep: weights->bf16 (W1 pre-scaled), packed gaussian params -
__global__ void prep_kernel(const float* __restrict__ means, const float* __restrict__ stds,
                            const float* __restrict__ W1, const float* __restrict__ W2,
                            unsigned short* __restrict__ W1bf, unsigned short* __restrict__ W2bf,
                            float* __restrict__ prm /* [512][2]: mis2, is2 */) {
  int t = blockIdx.x * blockDim.x + threadIdx.x;
  int stride = gridDim.x * blockDim.x;
  for (int i = t; i < 512 * 512; i += stride) W1bf[i] = f2bf(W1[i] * W1_SCALE);
  for (int i = t; i < 32 * 512; i += stride) W2bf[i] = f2bf(W2[i]);
  for (int i = t; i < 512; i += stride) {
    float s = fabsf(stds[i]) + 0.01f;
    float is2 = (1.0f / s) * IS2_SCALE;
    prm[2 * i] = -means[i] * is2;        // mis2
    prm[2 * i + 1] = is2;                // is2  (coef folded into W1)
  }
}

// ---------------- fused main kernel ------------------------------------------
// 1024 threads = 16 waves (4M x 4N), 128 rows/block, BK=32, triple-buffered B,
// ONE barrier per kb, half-split pipeline: B-frags always read one half-window
// before their MFMA; gauss(kb+1) computed behind MFMA half1. vmcnt(0) before
// the barrier certifies buf(kb+1) collectively (stage in flight 1 full kb).
__global__ __launch_bounds__(1024, 4) void fused_kernel(
    const float* __restrict__ rpe, const unsigned short* __restrict__ W1bf,
    const unsigned short* __restrict__ W2bf, const float* __restrict__ prm,
    const float* __restrict__ b1, const float* __restrict__ b2,
    float* __restrict__ out) {
  __shared__ __attribute__((aligned(16))) char lds[131072 + 4096 + 2048 + 2048];
  // [0,96K): 3x32KB B buffers; h[128][512] bf16 overlays [0,128K) after loop
  float* prm_s = (float*)(lds + 131072);                  // [512][2] = 4KB
  float* rpe_s = (float*)(lds + 131072 + 4096);           // [128][4] = 2KB
  float* b1_s  = (float*)(lds + 131072 + 4096 + 2048);    // [512]    = 2KB

  const int tid = threadIdx.x;
  const int rb = blockIdx.x * 128;

  if (tid < 512) rpe_s[tid] = rpe[rb * 4 + tid];
  prm_s[tid] = prm[tid];                 // 1024 floats
  if (tid < 512) b1_s[tid] = b1[tid];

  int goff[2];
#pragma unroll
  for (int i = 0; i < 2; ++i) {
    int c = i * 1024 + tid;
    int j = ((c >> 6) << 4) + (c & 15);
    goff[i] = j * 512 + ((c >> 4) & 3) * 8;
  }
  const char* Wc = (const char*)W1bf;

#define STAGE(buf, kb)                                                          \
  {                                                                             \
    _Pragma("unroll") for (int i_ = 0; i_ < 2; ++i_) {                          \
      const void* gp = (const void*)(Wc + (size_t)goff[i_] * 2 + (kb) * 64);    \
      void* lp = (void*)(lds + (buf) * 32768 + i_ * 16384 + tid * 16);          \
      __builtin_amdgcn_global_load_lds(                                         \
          (const __attribute__((address_space(1))) void*)gp,                    \
          (__attribute__((address_space(3))) void*)lp, 16, 0, 0);               \
    }                                                                           \
  }

  STAGE(0, 0);
  STAGE(1, 1);
  __syncthreads();   // full drain: rpe/prm/b1 + B slices 0,1 collectively ready

  const int w = tid >> 6, l = tid & 63;
  const int lr = l & 15, lg = l >> 4;
  const int mw = w >> 2, nw = w & 3;     // 4 M-waves x 4 N-waves
  const int r0 = mw * 32 + lr;           // A rows r0 and r0+16

  const f32x4 xa = *(const f32x4*)&rpe_s[r0 * 4];
  const f32x4 xb = *(const f32x4*)&rpe_s[(r0 + 16) * 4];
  const f32x4* prm4 = (const f32x4*)prm_s;

  f32x4 zv = {0.f, 0.f, 0.f, 0.f};
  f32x4 acc[2][8];
#pragma unroll
  for (int mf = 0; mf < 2; ++mf)
#pragma unroll
    for (int nf = 0; nf < 8; ++nf) acc[mf][nf] = zv;

  // ---- prologue: pre-read (kb=0, half0) B-frags + A(0)
  bfrag8 fA[4], fB[4];
  {
    const char* Bb = lds + nw * 8192 + lg * 256 + lr * 16;
#pragma unroll
    for (int nf = 0; nf < 4; ++nf) fA[nf] = *(const bfrag8*)(Bb + nf * 1024);
  }
  bfrag8 a0, a1;
  gauss_frags(prm4, xa, xb, 0, lg, &a0, &a1);

#pragma unroll
  for (int kb = 0; kb < 16; ++kb) {
    // ---- certify buf(kb+1) collectively: per-wave vmcnt(0) (only stage(kb+1)
    // outstanding, issued 1 kb ago) + rendezvous barrier.
    asm volatile("s_waitcnt vmcnt(0)" ::: "memory");
    __builtin_amdgcn_s_barrier();
    __builtin_amdgcn_sched_barrier(0);
    if (kb < 14) STAGE((kb + 2) % 3, kb + 2);

    // ---- hf0: issue reads half1, MFMA half0 (frags read last half-window)
    const char* Bb = lds + (kb % 3) * 32768 + nw * 8192 + lg * 256 + lr * 16;
    __builtin_amdgcn_s_setprio(1);
#pragma unroll
    for (int nf = 0; nf < 4; ++nf) fB[nf] = *(const bfrag8*)(Bb + (nf + 4) * 1024);
#pragma unroll
    for (int nf = 0; nf < 4; ++nf) {
      acc[0][nf] = __builtin_amdgcn_mfma_f32_16x16x32_bf16(a0, fA[nf], acc[0][nf], 0, 0, 0);
      acc[1][nf] = __builtin_amdgcn_mfma_f32_16x16x32_bf16(a1, fA[nf], acc[1][nf], 0, 0, 0);
    }
    __builtin_amdgcn_s_setprio(0);
    __builtin_amdgcn_sched_barrier(0);

    // ---- hf1: read-ahead (kb+1, half0) [certified by this kb's barrier],
    //           MFMA half1, gauss(kb+1) behind the MFMA issue
    __builtin_amdgcn_s_setprio(1);
    if (kb < 15) {
      const char* Bn = lds + ((kb + 1) % 3) * 32768 + nw * 8192 + lg * 256 + lr * 16;
#pragma unroll
      for (int nf = 0; nf < 4; ++nf) fA[nf] = *(const bfrag8*)(Bn + nf * 1024);
    }
#pragma unroll
    for (int nf = 0; nf < 4; ++nf) {
      acc[0][nf + 4] = __builtin_amdgcn_mfma_f32_16x16x32_bf16(a0, fB[nf], acc[0][nf + 4], 0, 0, 0);
      acc[1][nf + 4] = __builtin_amdgcn_mfma_f32_16x16x32_bf16(a1, fB[nf], acc[1][nf + 4], 0, 0, 0);
    }
    __builtin_amdgcn_s_setprio(0);
    if (kb < 15) gauss_frags(prm4, xa, xb, kb + 1, lg, &a0, &a1);
    __builtin_amdgcn_sched_barrier(0);
  }
  __syncthreads();   // all B reads done -> safe to overlay h on buffer region

  // ---- bias + fast GELU -> h in LDS [128][512] bf16, XOR-swizzled rows
  unsigned short* hbuf = (unsigned short*)lds;
#pragma unroll
  for (int mf = 0; mf < 2; ++mf) {
#pragma unroll
    for (int nf = 0; nf < 8; nf += 2) {
      int col0 = nw * 128 + nf * 16 + lr;
      int col1 = col0 + 16;
      float bb0 = b1_s[col0], bb1 = b1_s[col1];
#pragma unroll
      for (int bi = 0; bi < 4; ++bi) {
        float g0 = gelu_fast(acc[mf][nf][bi] + bb0);
        float g1 = gelu_fast(acc[mf][nf + 1][bi] + bb1);
        unsigned pr = cvtpk(g0, g1);
        int hrow = mw * 32 + mf * 16 + lg * 4 + bi;
        int base = hrow * 1024, sw = (hrow & 7) << 4;
        *(unsigned short*)((char*)hbuf + base + ((col0 * 2) ^ sw)) = (unsigned short)pr;
        *(unsigned short*)((char*)hbuf + base + ((col1 * 2) ^ sw)) = (unsigned short)(pr >> 16);
      }
    }
  }
  __syncthreads();

  // ---- GEMM2: out[128][32] = h @ W2^T. 16 waves: 8(row-tiles) x 2(col-tiles).
  const int rt = w >> 1, ct = w & 1;
  f32x4 acc2 = zv;
  const int row2 = rt * 16 + lr;
  for (int kb = 0; kb < 16; ++kb) {
    int cb = (kb * 64 + lg * 16) ^ ((row2 & 7) << 4);
    bfrag8 a = *(const bfrag8*)((char*)hbuf + row2 * 1024 + cb);
    bfrag8 b = *(const bfrag8*)(W2bf + (size_t)(ct * 16 + lr) * 512 + kb * 32 + lg * 8);
    acc2 = __builtin_amdgcn_mfma_f32_16x16x32_bf16(a, b, acc2, 0, 0, 0);
  }
  float b2v = b2[ct * 16 + lr];
  __syncthreads();                     // all h reads done -> safe to overlay

  float* ob = (float*)lds;             // [128][33] padded f32
#pragma unroll
  for (int bi = 0; bi < 4; ++bi)
    ob[(rt * 16 + lg * 4 + bi) * 33 + (ct * 16 + lr)] = acc2[bi] + b2v;
  __syncthreads();

  // ---- store transposed: out[b][o][m][n], 128 contiguous n per head
  const int bI = rb >> 16, mI = (rb >> 8) & 255, n0 = rb & 255;
  float* obase = out + ((size_t)(bI * 32) * 256 + mI) * 256 + n0;
#pragma unroll
  for (int p = 0; p < 4; ++p) {
    int e = tid + p * 1024;            // 0..4095
    int o = e >> 7, i = e & 127;
    obase[(size_t)o * 65536 + i] = ob[i * 33 + o];
  }
#undef STAGE
}

// ---------------- launch ------------------------------------------------------
extern "C" void kernel_launch(void* const* d_in, const int* in_sizes, int n_in,
                              void* d_out, int out_size, void* d_ws, size_t ws_size,
                              hipStream_t stream) {
  const float* rpe   = (const float*)d_in[0];
  const float* means = (const float*)d_in[1];
  const float* stds  = (const float*)d_in[2];
  const float* W1    = (const float*)d_in[3];
  const float* b1    = (const float*)d_in[4];
  const float* W2    = (const float*)d_in[5];
  const float* b2    = (const float*)d_in[6];
  float* out = (float*)d_out;

  char* ws = (char*)d_ws;
  unsigned short* W1bf = (unsigned short*)ws;             // 512*512*2 = 524288 B
  unsigned short* W2bf = (unsigned short*)(ws + 524288);  // 32*512*2  =  32768 B
  float* prm = (float*)(ws + 557056);                     // 512*2*4   =   4096 B

  prep_kernel<<<256, 256, 0, stream>>>(means, stds, W1, W2, W1bf, W2bf, prm);
  fused_kernel<<<2048, 1024, 0, stream>>>(rpe, W1bf, W2bf, prm, b1, b2, out);
}

// Round 18
// 257.179 us; speedup vs baseline: 1.9647x; 1.0568x over previous
//
#include <hip/hip_runtime.h>
#include <hip/hip_bf16.h>

typedef __attribute__((ext_vector_type(8))) short bfrag8;
typedef __attribute__((ext_vector_type(4))) float f32x4;
typedef __attribute__((ext_vector_type(4))) unsigned int u32x4;

#define IS2_SCALE 0.84932180028801907f   /* sqrt(0.5*log2(e)): exp2(-(u)^2)=exp(-t^2/2) */
#define W1_SCALE  0.46971724f            /* folds 1/(sqrt(2pi)*std) into W1 via is2 */

#if __has_builtin(__builtin_amdgcn_exp2f)
#define GEXP(x) __builtin_amdgcn_exp2f(x)
#else
__device__ __forceinline__ float gexp_asm(float x) {
  float r; asm("v_exp_f32 %0, %1" : "=v"(r) : "v"(x)); return r;
}
#define GEXP(x) gexp_asm(x)
#endif

__device__ __forceinline__ unsigned short f2bf(float x) {
  union { float f; unsigned u; } v; v.f = x;
  unsigned r = v.u + 0x7fffu + ((v.u >> 16) & 1u);
  return (unsigned short)(r >> 16);
}
__device__ __forceinline__ unsigned cvtpk(float lo, float hi) {
  unsigned r;
  asm("v_cvt_pk_bf16_f32 %0, %1, %2" : "=v"(r) : "v"(lo), "v"(hi));
  return r;
}
__device__ __forceinline__ float rcpa(float x) {
  float r; asm("v_rcp_f32 %0, %1" : "=v"(r) : "v"(x)); return r;
}
// tanh-form GELU: x/(1+exp2(x*(C0+C1*x^2)))
__device__ __forceinline__ float gelu_fast(float x) {
  float x2 = x * x;
  float w = __builtin_fmaf(x2, -0.1029488f, -2.3022078f);
  float e = GEXP(x * w);
  return x * rcpa(e + 1.0f);
}

// A-fragment pair (rows r0, r0+16) for K-block kb: 16 gaussians
__device__ __forceinline__ void gauss_frags(const f32x4* prm4, const f32x4 xa, const f32x4 xb,
                                            int kb, int lg, bfrag8* A0, bfrag8* A1) {
  const int k0 = kb * 32 + lg * 8;
  const float x0 = xa[kb >> 2], x1 = xb[kb >> 2];
  unsigned pk0[4], pk1[4];
#pragma unroll
  for (int q = 0; q < 4; ++q) {
    f32x4 P = prm4[(k0 >> 1) + q];     // {mis2_e, is2_e, mis2_o, is2_o}
    float u00 = __builtin_fmaf(x0, P[1], P[0]);
    float u01 = __builtin_fmaf(x0, P[3], P[2]);
    float u10 = __builtin_fmaf(x1, P[1], P[0]);
    float u11 = __builtin_fmaf(x1, P[3], P[2]);
    pk0[q] = cvtpk(P[1] * GEXP(-(u00 * u00)), P[3] * GEXP(-(u01 * u01)));
    pk1[q] = cvtpk(P[1] * GEXP(-(u10 * u10)), P[3] * GEXP(-(u11 * u11)));
  }
  u32x4 av0 = {pk0[0], pk0[1], pk0[2], pk0[3]};
  u32x4 av1 = {pk1[0], pk1[1], pk1[2], pk1[3]};
  *A0 = __builtin_bit_cast(bfrag8, av0);
  *A1 = __builtin_bit_cast(bfrag8, av1);
}

// ---------------- prep: weights->bf16 (W1 pre-scaled), packed gaussian params -
__global__ void prep_kernel(const float* __restrict__ means, const float* __restrict__ stds,
                            const float* __restrict__ W1, const float* __restrict__ W2,
                            unsigned short* __restrict__ W1bf, unsigned short* __restrict__ W2bf,
                            float* __restrict__ prm /* [512][2]: mis2, is2 */) {
  int t = blockIdx.x * blockDim.x + threadIdx.x;
  int stride = gridDim.x * blockDim.x;
  for (int i = t; i < 512 * 512; i += stride) W1bf[i] = f2bf(W1[i] * W1_SCALE);
  for (int i = t; i < 32 * 512; i += stride) W2bf[i] = f2bf(W2[i]);
  for (int i = t; i < 512; i += stride) {
    float s = fabsf(stds[i]) + 0.01f;
    float is2 = (1.0f / s) * IS2_SCALE;
    prm[2 * i] = -means[i] * is2;        // mis2
    prm[2 * i + 1] = is2;                // is2  (coef folded into W1)
  }
}

// ---------------- fused main kernel ------------------------------------------
// 1024 threads = 16 waves (4M x 4N), 128 rows/block, BK=32, triple-buffered B,
// ONE barrier per kb, half-split pipeline (R17). NEW: gaussian A-fragments
// computed by ONE producer wave per SIMD (w = 0,5,10,15; mw = 0..3) with a
// 2-ahead pipeline into a 3-slot LDS slice; all waves read a(kb+1) from the
// slice at the end of iter kb. Eval dup 4 -> 1 AND producers spread across
// SIMDs (the R14 flaw: producers 0,4,8,12 all hit SIMD 0).
__global__ __launch_bounds__(1024, 4) void fused_kernel(
    const float* __restrict__ rpe, const unsigned short* __restrict__ W1bf,
    const unsigned short* __restrict__ W2bf, const float* __restrict__ prm,
    const float* __restrict__ b1, const float* __restrict__ b2,
    float* __restrict__ out) {
  __shared__ __attribute__((aligned(16))) char lds[131072 + 4096 + 2048 + 2048];
  // [0,96K): 3x32KB B buffers; [96K,120K): gsl 3x8KB; h[128][512] overlays [0,128K)
  char*  gsl   = lds + 98304;                             // [3][4mw][2fr][4lg][16lr]x16B
  float* prm_s = (float*)(lds + 131072);                  // [512][2] = 4KB
  float* rpe_s = (float*)(lds + 131072 + 4096);           // [128][4] = 2KB
  float* b1_s  = (float*)(lds + 131072 + 4096 + 2048);    // [512]    = 2KB

  const int tid = threadIdx.x;
  const int rb = blockIdx.x * 128;

  if (tid < 512) rpe_s[tid] = rpe[rb * 4 + tid];
  prm_s[tid] = prm[tid];                 // 1024 floats
  if (tid < 512) b1_s[tid] = b1[tid];

  int goff[2];
#pragma unroll
  for (int i = 0; i < 2; ++i) {
    int c = i * 1024 + tid;
    int j = ((c >> 6) << 4) + (c & 15);
    goff[i] = j * 512 + ((c >> 4) & 3) * 8;
  }
  const char* Wc = (const char*)W1bf;

#define STAGE(buf, kb)                                                          \
  {                                                                             \
    _Pragma("unroll") for (int i_ = 0; i_ < 2; ++i_) {                          \
      const void* gp = (const void*)(Wc + (size_t)goff[i_] * 2 + (kb) * 64);    \
      void* lp = (void*)(lds + (buf) * 32768 + i_ * 16384 + tid * 16);          \
      __builtin_amdgcn_global_load_lds(                                         \
          (const __attribute__((address_space(1))) void*)gp,                    \
          (__attribute__((address_space(3))) void*)lp, 16, 0, 0);               \
    }                                                                           \
  }

  STAGE(0, 0);
  STAGE(1, 1);

  const int w = tid >> 6, l = tid & 63;
  const int lr = l & 15, lg = l >> 4;
  const int mw = w >> 2, nw = w & 3;     // 4 M-waves x 4 N-waves
  const int r0 = mw * 32 + lr;           // A rows r0 and r0+16
  const bool prod = (mw == nw);          // waves 0,5,10,15 -> one per SIMD

  const f32x4 xa = *(const f32x4*)&rpe_s[r0 * 4];
  const f32x4 xb = *(const f32x4*)&rpe_s[(r0 + 16) * 4];
  const f32x4* prm4 = (const f32x4*)prm_s;

  char* gbase = gsl + mw * 2048 + lg * 256 + lr * 16;   // + slot*8192, frag1 +1024

  __syncthreads();   // rpe/prm/b1 staged (needed by producers below); B 0,1 in flight

  // ---- prologue: producers fill slots 0,1
  if (prod) {
    bfrag8 t0, t1;
    gauss_frags(prm4, xa, xb, 0, lg, &t0, &t1);
    *(bfrag8*)(gbase) = t0;  *(bfrag8*)(gbase + 1024) = t1;
    gauss_frags(prm4, xa, xb, 1, lg, &t0, &t1);
    *(bfrag8*)(gbase + 8192) = t0;  *(bfrag8*)(gbase + 8192 + 1024) = t1;
  }
  __syncthreads();   // gsl slots 0,1 visible; B slices 0,1 drained (vmcnt in syncthreads)

  f32x4 zv = {0.f, 0.f, 0.f, 0.f};
  f32x4 acc[2][8];
#pragma unroll
  for (int mf = 0; mf < 2; ++mf)
#pragma unroll
    for (int nf = 0; nf < 8; ++nf) acc[mf][nf] = zv;

  // ---- pre-read A(0) + B(0, half0)
  bfrag8 acur0 = *(const bfrag8*)(gbase);
  bfrag8 acur1 = *(const bfrag8*)(gbase + 1024);
  bfrag8 fA[4], fB[4];
  {
    const char* Bb = lds + nw * 8192 + lg * 256 + lr * 16;
#pragma unroll
    for (int nf = 0; nf < 4; ++nf) fA[nf] = *(const bfrag8*)(Bb + nf * 1024);
  }

#pragma unroll
  for (int kb = 0; kb < 16; ++kb) {
    // certify buf(kb+1) (stage issued iter kb-1) + gsl slot(kb+1) writes
    asm volatile("s_waitcnt vmcnt(0)" ::: "memory");
    __builtin_amdgcn_s_barrier();
    __builtin_amdgcn_sched_barrier(0);
    if (kb < 14) STAGE((kb + 2) % 3, kb + 2);

    // ---- hf0: issue reads half1, MFMA half0
    const char* Bb = lds + (kb % 3) * 32768 + nw * 8192 + lg * 256 + lr * 16;
    __builtin_amdgcn_s_setprio(1);
#pragma unroll
    for (int nf = 0; nf < 4; ++nf) fB[nf] = *(const bfrag8*)(Bb + (nf + 4) * 1024);
#pragma unroll
    for (int nf = 0; nf < 4; ++nf) {
      acc[0][nf] = __builtin_amdgcn_mfma_f32_16x16x32_bf16(acur0, fA[nf], acc[0][nf], 0, 0, 0);
      acc[1][nf] = __builtin_amdgcn_mfma_f32_16x16x32_bf16(acur1, fA[nf], acc[1][nf], 0, 0, 0);
    }
    __builtin_amdgcn_s_setprio(0);
    __builtin_amdgcn_sched_barrier(0);

    // ---- hf1: read-ahead B(kb+1, half0), MFMA half1
    __builtin_amdgcn_s_setprio(1);
    if (kb < 15) {
      const char* Bn = lds + ((kb + 1) % 3) * 32768 + nw * 8192 + lg * 256 + lr * 16;
#pragma unroll
      for (int nf = 0; nf < 4; ++nf) fA[nf] = *(const bfrag8*)(Bn + nf * 1024);
    }
#pragma unroll
    for (int nf = 0; nf < 4; ++nf) {
      acc[0][nf + 4] = __builtin_amdgcn_mfma_f32_16x16x32_bf16(acur0, fB[nf], acc[0][nf + 4], 0, 0, 0);
      acc[1][nf + 4] = __builtin_amdgcn_mfma_f32_16x16x32_bf16(acur1, fB[nf], acc[1][nf + 4], 0, 0, 0);
    }
    __builtin_amdgcn_s_setprio(0);

    // ---- A pipeline: read a(kb+1) from slot (kb+1)%3 (written iter kb-1)
    if (kb < 15) {
      const char* gs = gbase + ((kb + 1) % 3) * 8192;
      acur0 = *(const bfrag8*)(gs);
      acur1 = *(const bfrag8*)(gs + 1024);
    }
    // ---- producer: gauss(kb+2) -> slot (kb+2)%3, drained before next barrier
    if (prod && kb < 14) {
      bfrag8 t0, t1;
      gauss_frags(prm4, xa, xb, kb + 2, lg, &t0, &t1);
      char* gd = gbase + ((kb + 2) % 3) * 8192;
      *(bfrag8*)(gd) = t0;  *(bfrag8*)(gd + 1024) = t1;
      asm volatile("s_waitcnt lgkmcnt(0)" ::: "memory");
    }
    __builtin_amdgcn_sched_barrier(0);
  }
  __syncthreads();   // all B/gsl reads done -> safe to overlay h

  // ---- bias + fast GELU -> h in LDS [128][512] bf16, XOR-swizzled rows
  unsigned short* hbuf = (unsigned short*)lds;
#pragma unroll
  for (int mf = 0; mf < 2; ++mf) {
#pragma unroll
    for (int nf = 0; nf < 8; nf += 2) {
      int col0 = nw * 128 + nf * 16 + lr;
      int col1 = col0 + 16;
      float bb0 = b1_s[col0], bb1 = b1_s[col1];
#pragma unroll
      for (int bi = 0; bi < 4; ++bi) {
        float g0 = gelu_fast(acc[mf][nf][bi] + bb0);
        float g1 = gelu_fast(acc[mf][nf + 1][bi] + bb1);
        unsigned pr = cvtpk(g0, g1);
        int hrow = mw * 32 + mf * 16 + lg * 4 + bi;
        int base = hrow * 1024, sw = (hrow & 7) << 4;
        *(unsigned short*)((char*)hbuf + base + ((col0 * 2) ^ sw)) = (unsigned short)pr;
        *(unsigned short*)((char*)hbuf + base + ((col1 * 2) ^ sw)) = (unsigned short)(pr >> 16);
      }
    }
  }
  __syncthreads();

  // ---- GEMM2: out[128][32] = h @ W2^T. 16 waves: 8(row-tiles) x 2(col-tiles).
  const int rt = w >> 1, ct = w & 1;
  f32x4 acc2 = zv;
  const int row2 = rt * 16 + lr;
  for (int kb = 0; kb < 16; ++kb) {
    int cb = (kb * 64 + lg * 16) ^ ((row2 & 7) << 4);
    bfrag8 a = *(const bfrag8*)((char*)hbuf + row2 * 1024 + cb);
    bfrag8 b = *(const bfrag8*)(W2bf + (size_t)(ct * 16 + lr) * 512 + kb * 32 + lg * 8);
    acc2 = __builtin_amdgcn_mfma_f32_16x16x32_bf16(a, b, acc2, 0, 0, 0);
  }
  float b2v = b2[ct * 16 + lr];
  __syncthreads();                     // all h reads done -> safe to overlay

  float* ob = (float*)lds;             // [128][33] padded f32
#pragma unroll
  for (int bi = 0; bi < 4; ++bi)
    ob[(rt * 16 + lg * 4 + bi) * 33 + (ct * 16 + lr)] = acc2[bi] + b2v;
  __syncthreads();

  // ---- store transposed: out[b][o][m][n], 128 contiguous n per head
  const int bI = rb >> 16, mI = (rb >> 8) & 255, n0 = rb & 255;
  float* obase = out + ((size_t)(bI * 32) * 256 + mI) * 256 + n0;
#pragma unroll
  for (int p = 0; p < 4; ++p) {
    int e = tid + p * 1024;            // 0..4095
    int o = e >> 7, i = e & 127;
    obase[(size_t)o * 65536 + i] = ob[i * 33 + o];
  }
#undef STAGE
}

// ---------------- launch ------------------------------------------------------
extern "C" void kernel_launch(void* const* d_in, const int* in_sizes, int n_in,
                              void* d_out, int out_size, void* d_ws, size_t ws_size,
                              hipStream_t stream) {
  const float* rpe   = (const float*)d_in[0];
  const float* means = (const float*)d_in[1];
  const float* stds  = (const float*)d_in[2];
  const float* W1    = (const float*)d_in[3];
  const float* b1    = (const float*)d_in[4];
  const float* W2    = (const float*)d_in[5];
  const float* b2    = (const float*)d_in[6];
  float* out = (float*)d_out;

  char* ws = (char*)d_ws;
  unsigned short* W1bf = (unsigned short*)ws;             // 512*512*2 = 524288 B
  unsigned short* W2bf = (unsigned short*)(ws + 524288);  // 32*512*2  =  32768 B
  float* prm = (float*)(ws + 557056);                     // 512*2*4   =   4096 B

  prep_kernel<<<256, 256, 0, stream>>>(means, stds, W1, W2, W1bf, W2bf, prm);
  fused_kernel<<<2048, 1024, 0, stream>>>(rpe, W1bf, W2bf, prm, b1, b2, out);
}